// Round 7
// baseline (218.072 us; speedup 1.0000x reference)
//
#include <hip/hip_runtime.h>

#define BB 16
#define NN 2000
#define HH 720
#define WW 1280
#define NPT (BB*NN)             // 32000 keypoints
#define PROJ_BLOCKS (NPT/256)   // 125 blocks, 1 thread per point
#define KSTRIDE 2048            // keybuf point stride
#define MAX_SEG 500             // max msegLen (ns=4)

static __device__ __forceinline__ unsigned u_min(unsigned a, unsigned b){ return a < b ? a : b; }

// median of 3 (unsigned) — single VOP3 v_med3_u32
static __device__ __forceinline__ unsigned u_med3(unsigned a, unsigned b, unsigned c) {
    unsigned d;
    asm("v_med3_u32 %0, %1, %2, %3" : "=v"(d) : "v"(a), "v"(b), "v"(c));
    return d;
}

// sorted top-5 insert (ascending uint keys): 1 v_min + 4 v_med3 = 5 VALU ops.
__device__ __forceinline__ void ins5(unsigned K[5], unsigned u) {
    K[4] = u_med3(K[3], K[4], u);
    K[3] = u_med3(K[2], K[3], u);
    K[2] = u_med3(K[1], K[2], u);
    K[1] = u_med3(K[0], K[1], u);
    K[0] = u_min(K[0], u);
}

// ---------------- bilinear sample, exact reference semantics (fallback) -----
__device__ __forceinline__ float bilin(const float* __restrict__ im, float px, float py) {
    px = fminf(fmaxf(px, 0.f), (float)(WW - 1));
    py = fminf(fmaxf(py, 0.f), (float)(HH - 1));
    float x0f = floorf(px), y0f = floorf(py);
    float fx = px - x0f, fy = py - y0f;
    int x0 = min(max((int)x0f, 0), WW - 1);
    int x1 = min(x0 + 1, WW - 1);
    int y0 = min(max((int)y0f, 0), HH - 1);
    int y1 = min(y0 + 1, HH - 1);
    const float* r0 = im + (size_t)y0 * WW;
    const float* r1 = im + (size_t)y1 * WW;
    float v00 = r0[x0], v01 = r0[x1], v10 = r1[x0], v11 = r1[x1];
    return (v00 * (1.f - fx) + v01 * fx) * (1.f - fy)
         + (v10 * (1.f - fx) + v11 * fx) * fy;
}

// ---------------- Kernel P0: projection + scalar losses ---------------------
__global__ __launch_bounds__(256) void project_kernel(
    const float* __restrict__ kpl, const float* __restrict__ kpr,
    const float* __restrict__ scores, const float* __restrict__ Q,
    float4* __restrict__ pts, float* __restrict__ partialsA,
    float* __restrict__ batch_acc, unsigned* __restrict__ dcnt)
{
    if (blockIdx.x == 0) {
        if (threadIdx.x < BB * 4) batch_acc[threadIdx.x] = 0.f;
        if (threadIdx.x == BB * 4) *dcnt = 0u;
    }
    int pt = blockIdx.x * 256 + threadIdx.x;      // < 32000 exactly
    int b  = pt / NN;

    float2 kl = ((const float2* __restrict__)kpl)[pt];
    float2 kr = ((const float2* __restrict__)kpr)[pt];
    float sc  = scores[pt];
    float ydiff = fabsf(kl.y - kr.y);

    const float* q = Q + b * 16;
    float dsp = kl.x - kr.x;
    float p0 = q[0]*kl.x  + q[1]*kl.y  + q[2]*dsp  + q[3];
    float p1 = q[4]*kl.x  + q[5]*kl.y  + q[6]*dsp  + q[7];
    float p2 = q[8]*kl.x  + q[9]*kl.y  + q[10]*dsp + q[11];
    float p3 = q[12]*kl.x + q[13]*kl.y + q[14]*dsp + q[15];
    float Wc = fmaxf(p3, 1e-6f);
    float X = p0 / Wc, Y = p1 / Wc, Z = p2 / Wc;
    bool valid = (Z > 100.f) && (Z < 30000.f) && (sc > 0.1f);
    float x  = X / 1000.f;
    float hh = Y / 1000.f;
    float y  = Z / 1000.f;
    float sq = x * x + y * y;
    if (!valid) { x = 0.f; y = 0.f; sq = 1e18f; }   // sentinel
    pts[pt] = make_float4(x, y, sq, hh);

    float s0 = sc, s1 = ydiff * sc, s2 = ydiff, s3 = (sc > 0.1f) ? 1.f : 0.f;
    #pragma unroll
    for (int off = 32; off > 0; off >>= 1) {
        s0 += __shfl_down(s0, off, 64);
        s1 += __shfl_down(s1, off, 64);
        s2 += __shfl_down(s2, off, 64);
        s3 += __shfl_down(s3, off, 64);
    }
    __shared__ float red[4][4];
    int wave = threadIdx.x >> 6, lane = threadIdx.x & 63;
    if (lane == 0) { red[wave][0]=s0; red[wave][1]=s1; red[wave][2]=s2; red[wave][3]=s3; }
    __syncthreads();
    if (threadIdx.x < 4) {
        int k = threadIdx.x;
        partialsA[blockIdx.x * 4 + k] = red[0][k] + red[1][k] + red[2][k] + red[3][k];
    }
}

// ---------------- Kernel S: per-batch counting sort of points by image row --
// order[b*NN+pos] = global pt index, sorted by floor(kyl). Pure permutation:
// patch results are stored by ORIGINAL pt index, so output bits are unchanged;
// only the memory-access order of the gathers improves (DRAM page/L2 lines).
__global__ __launch_bounds__(256) void sort_kernel(
    const float* __restrict__ kpl, int* __restrict__ order)
{
    int b = blockIdx.x;
    __shared__ int hist[720];
    __shared__ int wsum[4];
    for (int i = threadIdx.x; i < 720; i += 256) hist[i] = 0;
    __syncthreads();
    for (int p = threadIdx.x; p < NN; p += 256) {
        float y = kpl[2 * (b * NN + p) + 1];
        int bin = min(max((int)y, 0), 719);
        atomicAdd(&hist[bin], 1);
    }
    __syncthreads();
    int tid = threadIdx.x, lane = tid & 63, wv = tid >> 6;
    int h0 = 0, h1 = 0, h2 = 0;
    if (tid < 240) { h0 = hist[tid*3]; h1 = hist[tid*3+1]; h2 = hist[tid*3+2]; }
    int lsum = h0 + h1 + h2;
    int pre = lsum;
    #pragma unroll
    for (int off = 1; off < 64; off <<= 1) {
        int t = __shfl_up(pre, off, 64);
        if (lane >= off) pre += t;
    }
    if (lane == 63) wsum[wv] = pre;
    __syncthreads();
    int woff = 0;
    for (int k = 0; k < wv; ++k) woff += wsum[k];
    int excl = woff + pre - lsum;                 // exclusive start of this 3-bin chunk
    if (tid < 240) {
        hist[tid*3    ] = excl;
        hist[tid*3 + 1] = excl + h0;
        hist[tid*3 + 2] = excl + h0 + h1;
    }
    __syncthreads();
    for (int p = threadIdx.x; p < NN; p += 256) {
        float y = kpl[2 * (b * NN + p) + 1];
        int bin = min(max((int)y, 0), 719);
        int pos = atomicAdd(&hist[bin], 1);
        order[b * NN + pos] = b * NN + p;
    }
}

// ---------------- Kernel F1: fused patch + scan, PER-WAVE role mix ---------
// 320-thread blocks: waves 0..3 = patch (one row-sorted point each),
// wave 4 = KNN scan (64 n-points vs one LDS-staged 125-candidate segment).
// No __syncthreads anywhere: scan wave stages+consumes its own LDS; patch
// waves are LDS-free and store per-point partials directly (by ORIGINAL pt).
__global__ __launch_bounds__(320) void fused_patch_scan(
    const float* __restrict__ lg, const float* __restrict__ rg,
    const float* __restrict__ kpl, const float* __restrict__ kpr,
    const float* __restrict__ scores,
    const float4* __restrict__ pts, unsigned* __restrict__ keybuf,
    float4* __restrict__ partialsB, const int* __restrict__ order,
    int msegLen, int lns)
{
    __shared__ float4 seg[MAX_SEG];
    int wave = threadIdx.x >> 6, lane = threadIdx.x & 63;

    if (wave < 4) {
        // ================= patch wave: ONE row-sorted point =================
        int idx = blockIdx.x * 4 + wave;
        if (idx >= NPT) return;                    // wave-uniform
        int pt = order[idx];
        int b  = idx / NN;                         // sort is per-batch: idx/NN == pt/NN

        int rr = lane / 7, ci = lane - rr * 7;     // sample (row,col) for lane<49
        int s00 = lane + rr;                       // = rr*8+ci in 8x8 region
        if (s00 > 54) s00 = 54;
        int reg_r = lane >> 3, reg_c = lane & 7;   // region-load position

        const float* iml = lg + (size_t)b * (HH * WW);
        const float* imr = rg + (size_t)b * (HH * WW);
        float kxl = kpl[2*pt], kyl = kpl[2*pt+1];
        float kxr = kpr[2*pt], kyr = kpr[2*pt+1];
        float sc  = scores[pt];

        float flx = floorf(kxl), fly = floorf(kyl);
        float frx = floorf(kxr), fry = floorf(kyr);
        int xbl = (int)flx - 3, ybl = (int)fly - 3;
        int xbr = (int)frx - 3, ybr = (int)fry - 3;
        float fxl = kxl - flx, fyl = kyl - fly;
        float fxr = kxr - frx, fyr = kyr - fry;
        bool inL = (xbl >= 0) && (xbl <= WW-8) && (ybl >= 0) && (ybl <= HH-8);  // wave-uniform
        bool inR = (xbr >= 0) && (xbr <= WW-8) && (ybr >= 0) && (ybr <= HH-8);

        float regL = 0.f, regR = 0.f;              // both gathers in flight together
        if (inL) regL = iml[(size_t)(ybl + reg_r) * WW + xbl + reg_c];
        if (inR) regR = imr[(size_t)(ybr + reg_r) * WW + xbr + reg_c];

        float vl = 0.f, vr = 0.f;
        if (inL) {
            float v00 = __shfl(regL, s00,     64);
            float v01 = __shfl(regL, s00 + 1, 64);
            float v10 = __shfl(regL, s00 + 8, 64);
            float v11 = __shfl(regL, s00 + 9, 64);
            vl = (v00*(1.f-fxl) + v01*fxl)*(1.f-fyl) + (v10*(1.f-fxl) + v11*fxl)*fyl;
        } else if (lane < 49) {
            vl = bilin(iml, kxl + (float)(ci-3), kyl + (float)(rr-3));
        }
        if (inR) {
            float v00 = __shfl(regR, s00,     64);
            float v01 = __shfl(regR, s00 + 1, 64);
            float v10 = __shfl(regR, s00 + 8, 64);
            float v11 = __shfl(regR, s00 + 9, 64);
            vr = (v00*(1.f-fxr) + v01*fxr)*(1.f-fyr) + (v10*(1.f-fxr) + v11*fxr)*fyr;
        } else if (lane < 49) {
            vr = bilin(imr, kxr + (float)(ci-3), kyr + (float)(rr-3));
        }

        float adiff = (lane < 49) ? fabsf(vl - vr) : 0.f;
        float cl = __shfl(vl, 24, 64);   // center sample (3,3) = lane 24
        float cr = __shfl(vr, 24, 64);
        #pragma unroll
        for (int off = 32; off > 0; off >>= 1) adiff += __shfl_down(adiff, off, 64);

        if (lane == 0) {
            float isb = (cl > 0.02f) ? 1.f : 0.f;   // BRIGHT
            float w   = sc * isb;
            float dc  = fabsf(cl - cr);
            float sl1 = (dc < 1.f) ? 0.5f * dc * dc : dc - 0.5f;
            partialsB[pt] = make_float4(w, w * adiff * (1.f/49.f), sl1 * w, 0.f);
        }
    } else {
        // ================= scan wave: 64 n-points x one segment =================
        int ns  = 1 << lns;
        int sid = blockIdx.x;
        if (sid >= 32 * ns * BB) return;           // wave-uniform
        int bx2  = sid & 31;                       // 64-point chunk (32 x 64 = 2048 >= NN)
        int r    = sid >> 5;
        int segi = r & (ns - 1);
        int b    = r >> lns;
        int mseg0 = segi * msegLen;

        const float4* cand = pts + b * NN + mseg0;
        for (int j = lane; j < msegLen; j += 64) seg[j] = cand[j];
        asm volatile("s_waitcnt lgkmcnt(0)" ::: "memory");  // stage visible to whole wave

        int n  = bx2 * 64 + lane;
        int nc = (n < NN) ? n : (NN - 1);
        float4 me = pts[b * NN + nc];
        float nx2 = -2.f * me.x, ny2 = -2.f * me.y, sqn = me.z;

        unsigned K[5] = {0xFFFFFFFFu,0xFFFFFFFFu,0xFFFFFFFFu,0xFFFFFFFFu,0xFFFFFFFFu};

        int nb0 = bx2 * 64;
        bool has_self = (mseg0 < nb0 + 64) && (mseg0 + msegLen > nb0);  // wave-uniform

        if (has_self) {
            #pragma unroll 5
            for (int mm = 0; mm < msegLen; ++mm) {
                float4 o = seg[mm];                // LDS broadcast read
                int m = mseg0 + mm;
                float t = fmaf(ny2, o.y, o.z);
                t = fmaf(nx2, o.x, t);
                float d2 = fmaxf(t + sqn, 1e-12f);
                unsigned u = (__float_as_uint(d2) & 0xFFFFF800u) | (unsigned)m;
                u = (m == n) ? 0xFFFFFFFFu : u;    // exclude self
                ins5(K, u);
            }
        } else {
            #pragma unroll 5
            for (int mm = 0; mm < msegLen; ++mm) {
                float4 o = seg[mm];                // LDS broadcast read
                int m = mseg0 + mm;
                float t = fmaf(ny2, o.y, o.z);
                t = fmaf(nx2, o.x, t);
                float d2 = fmaxf(t + sqn, 1e-12f);
                unsigned u = (__float_as_uint(d2) & 0xFFFFF800u) | (unsigned)m;
                ins5(K, u);
            }
        }

        if (n < NN) {
            size_t base = (size_t)((b * ns + segi) * 5) * KSTRIDE + n;
            keybuf[base              ] = K[0];
            keybuf[base + KSTRIDE    ] = K[1];
            keybuf[base + KSTRIDE * 2] = K[2];
            keybuf[base + KSTRIDE * 3] = K[3];
            keybuf[base + KSTRIDE * 4] = K[4];
        }
    }
}

// ---------------- Kernel F2: merge + fused final epilogue -------------------
__global__ __launch_bounds__(256) void knn_merge_final(
    const float4* __restrict__ pts, const unsigned* __restrict__ keybuf,
    float* __restrict__ batch_acc, unsigned* __restrict__ dcnt,
    const float* __restrict__ partialsA, const float4* __restrict__ partialsB,
    float* __restrict__ out, int ns)
{
    int b = blockIdx.y;
    int n = blockIdx.x * 256 + threadIdx.x;

    float ls = 0.f, pen = 0.f, hacc = 0.f, cnt = 0.f;
    if (n < NN) {
        float4 me = pts[b * NN + n];
        if (me.z < 1e17f) {
            unsigned K[5] = {0xFFFFFFFFu,0xFFFFFFFFu,0xFFFFFFFFu,0xFFFFFFFFu,0xFFFFFFFFu};
            for (int s = 0; s < ns; ++s) {
                #pragma unroll
                for (int j = 0; j < 5; ++j) {
                    unsigned u = keybuf[(size_t)((b * ns + s) * 5 + j) * KSTRIDE + n];
                    ins5(K, u);
                }
            }
            float hsum = 0.f;
            #pragma unroll
            for (int t = 0; t < 5; ++t) {
                int idx = (int)(K[t] & 2047u);
                float4 o = pts[b * NN + idx];
                float dot = me.x * o.x + me.y * o.y;
                float d2 = (me.z + o.z) - 2.f * dot;        // exact recompute
                float nd = fmaxf(sqrtf(fmaxf(d2, 1e-12f)), 0.001f);
                hsum += o.w;
                pen  += fmaxf(fabsf(o.w - me.w) / nd - 0.4f, 0.f);
            }
            float lm = hsum / 5.f;
            float dd = fabsf(me.w - lm);
            ls = (dd < 0.01f) ? 0.5f * dd * dd / 0.01f : dd - 0.005f;  // smooth_l1 beta=0.01
            hacc = me.w;
            cnt  = 1.f;
        }
    }

    #pragma unroll
    for (int off = 32; off > 0; off >>= 1) {
        ls   += __shfl_down(ls,   off, 64);
        pen  += __shfl_down(pen,  off, 64);
        hacc += __shfl_down(hacc, off, 64);
        cnt  += __shfl_down(cnt,  off, 64);
    }
    __shared__ float r2[4][4];
    int wave = threadIdx.x >> 6, lane = threadIdx.x & 63;
    if (lane == 0) { r2[wave][0]=cnt; r2[wave][1]=ls; r2[wave][2]=pen; r2[wave][3]=hacc; }
    __syncthreads();
    if (threadIdx.x == 0) {
        float tc = r2[0][0]+r2[1][0]+r2[2][0]+r2[3][0];
        float tl = r2[0][1]+r2[1][1]+r2[2][1]+r2[3][1];
        float tp = r2[0][2]+r2[1][2]+r2[2][2]+r2[3][2];
        float th = r2[0][3]+r2[1][3]+r2[2][3]+r2[3][3];
        atomicAdd(&batch_acc[b * 4 + 0], tc);
        atomicAdd(&batch_acc[b * 4 + 1], tl);
        atomicAdd(&batch_acc[b * 4 + 2], tp);
        atomicAdd(&batch_acc[b * 4 + 3], th);
    }

    // ---- done-counter: last block runs the final scalar epilogue ----
    __shared__ int lastf;
    __threadfence();                                  // release our atomics
    if (threadIdx.x == 0) {
        unsigned old = atomicAdd(dcnt, 1u);
        lastf = (old == (unsigned)(8 * BB - 1)) ? 1 : 0;
    }
    __syncthreads();
    if (!lastf) return;
    __threadfence();                                  // acquire others' atomics

    float s[7] = {0,0,0,0,0,0,0};
    for (int rI = threadIdx.x; rI < PROJ_BLOCKS; rI += 256) {
        s[0] += partialsA[rI * 4 + 0];
        s[1] += partialsA[rI * 4 + 1];
        s[2] += partialsA[rI * 4 + 2];
        s[3] += partialsA[rI * 4 + 3];
    }
    for (int rI = threadIdx.x; rI < NPT; rI += 256) {
        float4 v = partialsB[rI];
        s[4] += v.x;
        s[5] += v.y;
        s[6] += v.z;
    }
    #pragma unroll
    for (int off = 32; off > 0; off >>= 1) {
        #pragma unroll
        for (int k = 0; k < 7; ++k) s[k] += __shfl_down(s[k], off, 64);
    }
    __shared__ float ws2[4][7];
    if (lane == 0) {
        #pragma unroll
        for (int k = 0; k < 7; ++k) ws2[wave][k] = s[k];
    }
    __syncthreads();
    if (threadIdx.x == 0) {
        float t[7];
        #pragma unroll
        for (int k = 0; k < 7; ++k)
            t[k] = ws2[0][k] + ws2[1][k] + ws2[2][k] + ws2[3][k];
        float ssc = t[0], yds = t[1], yd = t[2], cnts = t[3];
        float wsum = t[4], dw = t[5], iw = t[6];

        float l_epi = (ssc > 1e-4f) ? yds / fmaxf(ssc, 1e-12f) : yd / (float)NPT;
        float safe = fmaxf(wsum, 1e-12f);
        float l_photo = (wsum > 1e-4f) ? (dw / safe + iw / safe) : 0.f;

        float als = 0.f, alsl = 0.f, alz = 0.f, okc = 0.f;
        for (int bb = 0; bb < BB; ++bb) {
            float nvf  = __hip_atomic_load(&batch_acc[bb*4+0], __ATOMIC_RELAXED, __HIP_MEMORY_SCOPE_AGENT);
            float lsb  = __hip_atomic_load(&batch_acc[bb*4+1], __ATOMIC_RELAXED, __HIP_MEMORY_SCOPE_AGENT);
            float penb = __hip_atomic_load(&batch_acc[bb*4+2], __ATOMIC_RELAXED, __HIP_MEMORY_SCOPE_AGENT);
            float hb   = __hip_atomic_load(&batch_acc[bb*4+3], __ATOMIC_RELAXED, __HIP_MEMORY_SCOPE_AGENT);
            float nv = fmaxf(nvf, 1.f);
            float ok = (nvf >= 10.f) ? 1.f : 0.f;
            als  += ok * (lsb / nv);
            alsl += ok * (penb / (nv * 5.f));   // K = 5
            alz  += ok * fabsf(hb / nv);
            okc  += ok;
        }
        float nb = fmaxf(okc, 1.f);
        bool gate = (cnts >= 10.f) && (okc > 0.f);
        out[0] = l_photo;
        out[1] = l_epi;
        out[2] = gate ? als / nb : 0.f;
        out[3] = gate ? alsl / nb : 0.f;
        out[4] = gate ? alz / nb : 0.f;
    }
}

extern "C" void kernel_launch(void* const* d_in, const int* in_sizes, int n_in,
                              void* d_out, int out_size, void* d_ws, size_t ws_size,
                              hipStream_t stream)
{
    const float* lg     = (const float*)d_in[0];
    const float* rg     = (const float*)d_in[1];
    const float* kpl    = (const float*)d_in[2];
    const float* kpr    = (const float*)d_in[3];
    const float* scores = (const float*)d_in[4];
    const float* Q      = (const float*)d_in[5];
    float* out = (float*)d_out;

    char* ws = (char*)d_ws;
    float4*   pts       = (float4*)ws;                   // 512000 B
    float*    partialsA = (float*)(ws + 512000);         // 125*4*4 = 2000 B (pad 2048)
    int*      order     = (int*)(ws + 514048);           // 32000*4 = 128000 B
    float4*   partialsB = (float4*)(ws + 642048);        // 32000*16 = 512000 B
    float*    batch_acc = (float*)(ws + 1154048);        // 16*4*4 = 256 B
    unsigned* dcnt      = (unsigned*)(ws + 1154304);     // 4 B (pad 256)
    unsigned* keybuf    = (unsigned*)(ws + 1154560);

    // pick largest NSPLIT whose keybuf fits ws (deterministic: ws_size constant)
    int ns = 16;
    if (ws_size < 1154560 + (size_t)BB * 16 * 5 * KSTRIDE * 4) ns = 8;
    if (ws_size < 1154560 + (size_t)BB *  8 * 5 * KSTRIDE * 4) ns = 4;
    int lns = (ns == 16) ? 4 : ((ns == 8) ? 3 : 2);
    int msegLen = NN / ns;

    int nsActive = 32 * ns * BB;                  // scan-wave count (ns=16: 8192)
    int nblk = (NPT + 3) / 4;                     // 8000 patch blocks minimum
    if (nsActive > nblk) nblk = nsActive;         // ns=16 -> 8192 blocks

    project_kernel<<<PROJ_BLOCKS, 256, 0, stream>>>(kpl, kpr, scores, Q,
                                                    pts, partialsA, batch_acc, dcnt);
    sort_kernel<<<BB, 256, 0, stream>>>(kpl, order);
    fused_patch_scan<<<nblk, 320, 0, stream>>>(
        lg, rg, kpl, kpr, scores, pts, keybuf, partialsB, order, msegLen, lns);
    knn_merge_final<<<dim3(8, BB), 256, 0, stream>>>(pts, keybuf, batch_acc, dcnt,
                                                     partialsA, partialsB, out, ns);
}

// Round 8
// 173.494 us; speedup vs baseline: 1.2569x; 1.2569x over previous
//
#include <hip/hip_runtime.h>

#define BB 16
#define NN 2000
#define HH 720
#define WW 1280
#define NPT (BB*NN)             // 32000 keypoints
#define PATCH_BLOCKS 1000       // 4 waves x 8 points each
#define PROJ_BLOCKS (NPT/256)   // 125 blocks, 1 thread per point
#define KSTRIDE 2048            // keybuf point stride
#define NS 4                    // KNN segment split (compile-time!)
#define SEGLEN (NN/NS)          // 500 candidates per segment
#define SCAN_BLOCKS (8*NS*BB)   // 512 scan blocks
#define FUSED_BLOCKS 1536       // 1024 patch slots (1000 used) + 512 scan, 2:1

static __device__ __forceinline__ unsigned u_min(unsigned a, unsigned b){ return a < b ? a : b; }

// median of 3 (unsigned) — single VOP3 v_med3_u32
static __device__ __forceinline__ unsigned u_med3(unsigned a, unsigned b, unsigned c) {
    unsigned d;
    asm("v_med3_u32 %0, %1, %2, %3" : "=v"(d) : "v"(a), "v"(b), "v"(c));
    return d;
}

// sorted top-5 insert (ascending uint keys): 1 v_min + 4 v_med3 = 5 VALU ops.
__device__ __forceinline__ void ins5(unsigned K[5], unsigned u) {
    K[4] = u_med3(K[3], K[4], u);
    K[3] = u_med3(K[2], K[3], u);
    K[2] = u_med3(K[1], K[2], u);
    K[1] = u_med3(K[0], K[1], u);
    K[0] = u_min(K[0], u);
}

// ---------------- bilinear sample, exact reference semantics (fallback) -----
__device__ __forceinline__ float bilin(const float* __restrict__ im, float px, float py) {
    px = fminf(fmaxf(px, 0.f), (float)(WW - 1));
    py = fminf(fmaxf(py, 0.f), (float)(HH - 1));
    float x0f = floorf(px), y0f = floorf(py);
    float fx = px - x0f, fy = py - y0f;
    int x0 = min(max((int)x0f, 0), WW - 1);
    int x1 = min(x0 + 1, WW - 1);
    int y0 = min(max((int)y0f, 0), HH - 1);
    int y1 = min(y0 + 1, HH - 1);
    const float* r0 = im + (size_t)y0 * WW;
    const float* r1 = im + (size_t)y1 * WW;
    float v00 = r0[x0], v01 = r0[x1], v10 = r1[x0], v11 = r1[x1];
    return (v00 * (1.f - fx) + v01 * fx) * (1.f - fy)
         + (v10 * (1.f - fx) + v11 * fx) * fy;
}

// ---------------- Kernel P0: projection + scalar losses ---------------------
__global__ __launch_bounds__(256) void project_kernel(
    const float* __restrict__ kpl, const float* __restrict__ kpr,
    const float* __restrict__ scores, const float* __restrict__ Q,
    float4* __restrict__ pts, float* __restrict__ partialsA,
    float* __restrict__ batch_acc, unsigned* __restrict__ dcnt)
{
    if (blockIdx.x == 0) {
        if (threadIdx.x < BB * 4) batch_acc[threadIdx.x] = 0.f;
        if (threadIdx.x == BB * 4) *dcnt = 0u;
    }
    int pt = blockIdx.x * 256 + threadIdx.x;      // < 32000 exactly
    int b  = pt / NN;

    float2 kl = ((const float2* __restrict__)kpl)[pt];
    float2 kr = ((const float2* __restrict__)kpr)[pt];
    float sc  = scores[pt];
    float ydiff = fabsf(kl.y - kr.y);

    const float* q = Q + b * 16;
    float dsp = kl.x - kr.x;
    float p0 = q[0]*kl.x  + q[1]*kl.y  + q[2]*dsp  + q[3];
    float p1 = q[4]*kl.x  + q[5]*kl.y  + q[6]*dsp  + q[7];
    float p2 = q[8]*kl.x  + q[9]*kl.y  + q[10]*dsp + q[11];
    float p3 = q[12]*kl.x + q[13]*kl.y + q[14]*dsp + q[15];
    float Wc = fmaxf(p3, 1e-6f);
    float X = p0 / Wc, Y = p1 / Wc, Z = p2 / Wc;
    bool valid = (Z > 100.f) && (Z < 30000.f) && (sc > 0.1f);
    float x  = X / 1000.f;
    float hh = Y / 1000.f;
    float y  = Z / 1000.f;
    float sq = x * x + y * y;
    if (!valid) { x = 0.f; y = 0.f; sq = 1e18f; }   // sentinel
    pts[pt] = make_float4(x, y, sq, hh);

    float s0 = sc, s1 = ydiff * sc, s2 = ydiff, s3 = (sc > 0.1f) ? 1.f : 0.f;
    #pragma unroll
    for (int off = 32; off > 0; off >>= 1) {
        s0 += __shfl_down(s0, off, 64);
        s1 += __shfl_down(s1, off, 64);
        s2 += __shfl_down(s2, off, 64);
        s3 += __shfl_down(s3, off, 64);
    }
    __shared__ float red[4][4];
    int wave = threadIdx.x >> 6, lane = threadIdx.x & 63;
    if (lane == 0) { red[wave][0]=s0; red[wave][1]=s1; red[wave][2]=s2; red[wave][3]=s3; }
    __syncthreads();
    if (threadIdx.x < 4) {
        int k = threadIdx.x;
        partialsA[blockIdx.x * 4 + k] = red[0][k] + red[1][k] + red[2][k] + red[3][k];
    }
}

// ---------------- Kernel F1: fused patch loss + KNN scan -------------------
// Best-measured structure (178.7 µs total): patch = 1000 blocks, 4 waves x
// 8 pts, per-lane a4 accumulation + one reduce; scan = LDS-staged segment.
// Change this round: NS=4 (500-cand segments) — same total scan work, 1/4
// the keybuf rows -> merge chain 80 -> 20 loads and keybuf 10.5 -> 2.6 MB.
// Roles interleaved 2 patch : 1 scan in dispatch order.
__global__ __launch_bounds__(256) void fused_patch_scan(
    const float* __restrict__ lg, const float* __restrict__ rg,
    const float* __restrict__ kpl, const float* __restrict__ kpr,
    const float* __restrict__ scores,
    const float4* __restrict__ pts, unsigned* __restrict__ keybuf,
    float* __restrict__ partialsB)
{
    int i = blockIdx.x;
    int m3 = i % 3;

    if (m3 != 2) {
        // ================= patch-loss path =================
        int pid = (i / 3) * 2 + m3;                // [0, 1024)
        if (pid >= PATCH_BLOCKS) return;           // padding (whole block exits)
        int wave = threadIdx.x >> 6, lane = threadIdx.x & 63;
        int rr = lane / 7, ci = lane - rr * 7;     // sample (row,col) for lane<49
        int s00 = lane + rr;                       // = rr*8+ci in 8x8 region
        if (s00 > 54) s00 = 54;                    // keep shfl idx valid for lanes>=49
        int reg_r = lane >> 3, reg_c = lane & 7;   // region-load position

        float a3 = 0.f, a4l = 0.f, a5 = 0.f;       // a3/a5 uniform, a4l per-lane

        for (int it = 0; it < 8; ++it) {
            int pt = pid * 32 + wave * 8 + it;
            int b = pt / NN;
            const float* iml = lg + (size_t)b * (HH * WW);
            const float* imr = rg + (size_t)b * (HH * WW);
            float kxl = kpl[2*pt], kyl = kpl[2*pt+1];
            float kxr = kpr[2*pt], kyr = kpr[2*pt+1];
            float sc  = scores[pt];

            // ---- left patch ----
            float flx = floorf(kxl), fly = floorf(kyl);
            int xbl = (int)flx - 3, ybl = (int)fly - 3;
            float fxl = kxl - flx, fyl = kyl - fly;
            float vl = 0.f;
            if (xbl >= 0 && xbl <= WW-8 && ybl >= 0 && ybl <= HH-8) {  // wave-uniform
                float reg = iml[(size_t)(ybl + reg_r) * WW + xbl + reg_c];
                float v00 = __shfl(reg, s00,     64);
                float v01 = __shfl(reg, s00 + 1, 64);
                float v10 = __shfl(reg, s00 + 8, 64);
                float v11 = __shfl(reg, s00 + 9, 64);
                vl = (v00*(1.f-fxl) + v01*fxl)*(1.f-fyl) + (v10*(1.f-fxl) + v11*fxl)*fyl;
            } else if (lane < 49) {
                vl = bilin(iml, kxl + (float)(ci-3), kyl + (float)(rr-3));
            }
            // ---- right patch ----
            float frx = floorf(kxr), fry = floorf(kyr);
            int xbr = (int)frx - 3, ybr = (int)fry - 3;
            float fxr = kxr - frx, fyr = kyr - fry;
            float vr = 0.f;
            if (xbr >= 0 && xbr <= WW-8 && ybr >= 0 && ybr <= HH-8) {  // wave-uniform
                float reg = imr[(size_t)(ybr + reg_r) * WW + xbr + reg_c];
                float v00 = __shfl(reg, s00,     64);
                float v01 = __shfl(reg, s00 + 1, 64);
                float v10 = __shfl(reg, s00 + 8, 64);
                float v11 = __shfl(reg, s00 + 9, 64);
                vr = (v00*(1.f-fxr) + v01*fxr)*(1.f-fyr) + (v10*(1.f-fxr) + v11*fxr)*fyr;
            } else if (lane < 49) {
                vr = bilin(imr, kxr + (float)(ci-3), kyr + (float)(rr-3));
            }

            float adiff = (lane < 49) ? fabsf(vl - vr) : 0.f;
            float cl = __shfl(vl, 24, 64);   // center sample (3,3) = lane 24
            float cr = __shfl(vr, 24, 64);

            float isb = (cl > 0.02f) ? 1.f : 0.f;   // BRIGHT
            float w   = sc * isb;
            float dc  = fabsf(cl - cr);
            float sl1 = (dc < 1.f) ? 0.5f * dc * dc : dc - 0.5f;

            a3 += w;            // identical on every lane
            a5 += sl1 * w;      // identical on every lane
            a4l += w * adiff;   // per-lane; reduce once below
        }

        #pragma unroll
        for (int off = 32; off > 0; off >>= 1) a4l += __shfl_down(a4l, off, 64);

        __shared__ float red[4][3];
        if (lane == 0) { red[wave][0]=a3; red[wave][1]=a4l * (1.f/49.f); red[wave][2]=a5; }
        __syncthreads();
        if (threadIdx.x < 4) {
            int k = threadIdx.x;
            float v = 0.f;
            if (k < 3) v = red[0][k] + red[1][k] + red[2][k] + red[3][k];
            partialsB[pid * 4 + k] = v;
        }
    } else {
        // ================= KNN scan path (LDS-staged, NS=4) =================
        __shared__ float4 seg[SEGLEN];             // 500 candidates = 8 KB
        int sid = i / 3;                           // [0, 512)
        int bx   = sid & 7;
        int r    = sid >> 3;
        int segi = r & (NS - 1);
        int b    = r >> 2;                         // log2(NS)=2
        int mseg0 = segi * SEGLEN;
        int n = bx * 256 + threadIdx.x;
        int nc = (n < NN) ? n : (NN - 1);          // clamp for safe loads

        const float4* cand = pts + b * NN + mseg0;
        for (int j = threadIdx.x; j < SEGLEN; j += 256) seg[j] = cand[j];

        float4 me = pts[b * NN + nc];
        float nx2 = -2.f * me.x, ny2 = -2.f * me.y, sqn = me.z;

        unsigned K[5] = {0xFFFFFFFFu,0xFFFFFFFFu,0xFFFFFFFFu,0xFFFFFFFFu,0xFFFFFFFFu};

        int nb0 = bx * 256;
        bool has_self = (mseg0 < nb0 + 256) && (mseg0 + SEGLEN > nb0);  // block-uniform

        __syncthreads();

        if (has_self) {
            #pragma unroll 5
            for (int mm = 0; mm < SEGLEN; ++mm) {
                float4 o = seg[mm];                // LDS broadcast read
                int m = mseg0 + mm;
                float t = fmaf(ny2, o.y, o.z);
                t = fmaf(nx2, o.x, t);
                float d2 = fmaxf(t + sqn, 1e-12f);
                unsigned u = (__float_as_uint(d2) & 0xFFFFF800u) | (unsigned)m;
                u = (m == n) ? 0xFFFFFFFFu : u;    // exclude self
                ins5(K, u);
            }
        } else {
            #pragma unroll 5
            for (int mm = 0; mm < SEGLEN; ++mm) {
                float4 o = seg[mm];                // LDS broadcast read
                int m = mseg0 + mm;
                float t = fmaf(ny2, o.y, o.z);
                t = fmaf(nx2, o.x, t);
                float d2 = fmaxf(t + sqn, 1e-12f);
                unsigned u = (__float_as_uint(d2) & 0xFFFFF800u) | (unsigned)m;
                ins5(K, u);
            }
        }

        if (n < NN) {
            size_t base = (size_t)((b * NS + segi) * 5) * KSTRIDE + n;
            keybuf[base              ] = K[0];
            keybuf[base + KSTRIDE    ] = K[1];
            keybuf[base + KSTRIDE * 2] = K[2];
            keybuf[base + KSTRIDE * 3] = K[3];
            keybuf[base + KSTRIDE * 4] = K[4];
        }
    }
}

// ---------------- Kernel F2: merge + fused final epilogue -------------------
// NS is compile-time: the 4x5 = 20 keybuf loads fully unroll and issue with
// maximum MLP (the r7 regression exposed this kernel as latency-bound).
__global__ __launch_bounds__(256) void knn_merge_final(
    const float4* __restrict__ pts, const unsigned* __restrict__ keybuf,
    float* __restrict__ batch_acc, unsigned* __restrict__ dcnt,
    const float* __restrict__ partialsA, const float* __restrict__ partialsB,
    float* __restrict__ out)
{
    int b = blockIdx.y;
    int n = blockIdx.x * 256 + threadIdx.x;

    float ls = 0.f, pen = 0.f, hacc = 0.f, cnt = 0.f;
    if (n < NN) {
        float4 me = pts[b * NN + n];
        if (me.z < 1e17f) {
            unsigned K[5] = {0xFFFFFFFFu,0xFFFFFFFFu,0xFFFFFFFFu,0xFFFFFFFFu,0xFFFFFFFFu};
            #pragma unroll
            for (int s = 0; s < NS; ++s) {
                #pragma unroll
                for (int j = 0; j < 5; ++j) {
                    unsigned u = keybuf[(size_t)((b * NS + s) * 5 + j) * KSTRIDE + n];
                    ins5(K, u);
                }
            }
            float hsum = 0.f;
            #pragma unroll
            for (int t = 0; t < 5; ++t) {
                int idx = (int)(K[t] & 2047u);
                float4 o = pts[b * NN + idx];
                float dot = me.x * o.x + me.y * o.y;
                float d2 = (me.z + o.z) - 2.f * dot;        // exact recompute
                float nd = fmaxf(sqrtf(fmaxf(d2, 1e-12f)), 0.001f);
                hsum += o.w;
                pen  += fmaxf(fabsf(o.w - me.w) / nd - 0.4f, 0.f);
            }
            float lm = hsum / 5.f;
            float dd = fabsf(me.w - lm);
            ls = (dd < 0.01f) ? 0.5f * dd * dd / 0.01f : dd - 0.005f;  // smooth_l1 beta=0.01
            hacc = me.w;
            cnt  = 1.f;
        }
    }

    #pragma unroll
    for (int off = 32; off > 0; off >>= 1) {
        ls   += __shfl_down(ls,   off, 64);
        pen  += __shfl_down(pen,  off, 64);
        hacc += __shfl_down(hacc, off, 64);
        cnt  += __shfl_down(cnt,  off, 64);
    }
    __shared__ float r2[4][4];
    int wave = threadIdx.x >> 6, lane = threadIdx.x & 63;
    if (lane == 0) { r2[wave][0]=cnt; r2[wave][1]=ls; r2[wave][2]=pen; r2[wave][3]=hacc; }
    __syncthreads();
    if (threadIdx.x == 0) {
        float tc = r2[0][0]+r2[1][0]+r2[2][0]+r2[3][0];
        float tl = r2[0][1]+r2[1][1]+r2[2][1]+r2[3][1];
        float tp = r2[0][2]+r2[1][2]+r2[2][2]+r2[3][2];
        float th = r2[0][3]+r2[1][3]+r2[2][3]+r2[3][3];
        atomicAdd(&batch_acc[b * 4 + 0], tc);
        atomicAdd(&batch_acc[b * 4 + 1], tl);
        atomicAdd(&batch_acc[b * 4 + 2], tp);
        atomicAdd(&batch_acc[b * 4 + 3], th);
    }

    // ---- done-counter: last block runs the final scalar epilogue ----
    __shared__ int lastf;
    __threadfence();                                  // release our atomics
    if (threadIdx.x == 0) {
        unsigned old = atomicAdd(dcnt, 1u);
        lastf = (old == (unsigned)(8 * BB - 1)) ? 1 : 0;
    }
    __syncthreads();
    if (!lastf) return;
    __threadfence();                                  // acquire others' atomics

    float s[7] = {0,0,0,0,0,0,0};
    for (int rI = threadIdx.x; rI < PROJ_BLOCKS; rI += 256) {
        s[0] += partialsA[rI * 4 + 0];
        s[1] += partialsA[rI * 4 + 1];
        s[2] += partialsA[rI * 4 + 2];
        s[3] += partialsA[rI * 4 + 3];
    }
    for (int rI = threadIdx.x; rI < PATCH_BLOCKS; rI += 256) {
        s[4] += partialsB[rI * 4 + 0];
        s[5] += partialsB[rI * 4 + 1];
        s[6] += partialsB[rI * 4 + 2];
    }
    #pragma unroll
    for (int off = 32; off > 0; off >>= 1) {
        #pragma unroll
        for (int k = 0; k < 7; ++k) s[k] += __shfl_down(s[k], off, 64);
    }
    __shared__ float ws2[4][7];
    if (lane == 0) {
        #pragma unroll
        for (int k = 0; k < 7; ++k) ws2[wave][k] = s[k];
    }
    __syncthreads();
    if (threadIdx.x == 0) {
        float t[7];
        #pragma unroll
        for (int k = 0; k < 7; ++k)
            t[k] = ws2[0][k] + ws2[1][k] + ws2[2][k] + ws2[3][k];
        float ssc = t[0], yds = t[1], yd = t[2], cnts = t[3];
        float wsum = t[4], dw = t[5], iw = t[6];

        float l_epi = (ssc > 1e-4f) ? yds / fmaxf(ssc, 1e-12f) : yd / (float)NPT;
        float safe = fmaxf(wsum, 1e-12f);
        float l_photo = (wsum > 1e-4f) ? (dw / safe + iw / safe) : 0.f;

        float als = 0.f, alsl = 0.f, alz = 0.f, okc = 0.f;
        for (int bb = 0; bb < BB; ++bb) {
            float nvf  = __hip_atomic_load(&batch_acc[bb*4+0], __ATOMIC_RELAXED, __HIP_MEMORY_SCOPE_AGENT);
            float lsb  = __hip_atomic_load(&batch_acc[bb*4+1], __ATOMIC_RELAXED, __HIP_MEMORY_SCOPE_AGENT);
            float penb = __hip_atomic_load(&batch_acc[bb*4+2], __ATOMIC_RELAXED, __HIP_MEMORY_SCOPE_AGENT);
            float hb   = __hip_atomic_load(&batch_acc[bb*4+3], __ATOMIC_RELAXED, __HIP_MEMORY_SCOPE_AGENT);
            float nv = fmaxf(nvf, 1.f);
            float ok = (nvf >= 10.f) ? 1.f : 0.f;
            als  += ok * (lsb / nv);
            alsl += ok * (penb / (nv * 5.f));   // K = 5
            alz  += ok * fabsf(hb / nv);
            okc  += ok;
        }
        float nb = fmaxf(okc, 1.f);
        bool gate = (cnts >= 10.f) && (okc > 0.f);
        out[0] = l_photo;
        out[1] = l_epi;
        out[2] = gate ? als / nb : 0.f;
        out[3] = gate ? alsl / nb : 0.f;
        out[4] = gate ? alz / nb : 0.f;
    }
}

extern "C" void kernel_launch(void* const* d_in, const int* in_sizes, int n_in,
                              void* d_out, int out_size, void* d_ws, size_t ws_size,
                              hipStream_t stream)
{
    const float* lg     = (const float*)d_in[0];
    const float* rg     = (const float*)d_in[1];
    const float* kpl    = (const float*)d_in[2];
    const float* kpr    = (const float*)d_in[3];
    const float* scores = (const float*)d_in[4];
    const float* Q      = (const float*)d_in[5];
    float* out = (float*)d_out;

    char* ws = (char*)d_ws;
    float4*   pts       = (float4*)ws;                   // 512000 B
    float*    partialsA = (float*)(ws + 512000);         // 125*4*4 = 2000 B (pad 2048)
    float*    partialsB = (float*)(ws + 514048);         // 1000*4*4 = 16000 B (pad 16384)
    float*    batch_acc = (float*)(ws + 530432);         // 16*4*4 = 256 B
    unsigned* dcnt      = (unsigned*)(ws + 530688);      // 4 B (pad 256)
    unsigned* keybuf    = (unsigned*)(ws + 530944);      // 16*4*5*2048*4 = 2,621,440 B
                                                         // total 3.15 MB << ws

    project_kernel<<<PROJ_BLOCKS, 256, 0, stream>>>(kpl, kpr, scores, Q,
                                                    pts, partialsA, batch_acc, dcnt);
    fused_patch_scan<<<FUSED_BLOCKS, 256, 0, stream>>>(
        lg, rg, kpl, kpr, scores, pts, keybuf, partialsB);
    knn_merge_final<<<dim3(8, BB), 256, 0, stream>>>(pts, keybuf, batch_acc, dcnt,
                                                     partialsA, partialsB, out);
}

// Round 9
// 172.750 us; speedup vs baseline: 1.2624x; 1.0043x over previous
//
#include <hip/hip_runtime.h>

#define BB 16
#define NN 2000
#define HH 720
#define WW 1280
#define NPT (BB*NN)             // 32000 keypoints
#define PATCH_BLOCKS 1000       // 4 waves x 8 points each
#define PROJ_BLOCKS (NPT/256)   // 125 blocks, 1 thread per point
#define KSTRIDE 2048            // keybuf point stride
#define NS 4                    // KNN segment split (compile-time)
#define SEGLEN (NN/NS)          // 500 candidates per segment
#define FUSED_BLOCKS (PROJ_BLOCKS + 1536)   // 125 proj + 1024 patch slots + 512 scan

static __device__ __forceinline__ unsigned u_min(unsigned a, unsigned b){ return a < b ? a : b; }

// median of 3 (unsigned) — single VOP3 v_med3_u32
static __device__ __forceinline__ unsigned u_med3(unsigned a, unsigned b, unsigned c) {
    unsigned d;
    asm("v_med3_u32 %0, %1, %2, %3" : "=v"(d) : "v"(a), "v"(b), "v"(c));
    return d;
}

// sorted top-5 insert (ascending uint keys): 1 v_min + 4 v_med3 = 5 VALU ops.
__device__ __forceinline__ void ins5(unsigned K[5], unsigned u) {
    K[4] = u_med3(K[3], K[4], u);
    K[3] = u_med3(K[2], K[3], u);
    K[2] = u_med3(K[1], K[2], u);
    K[1] = u_med3(K[0], K[1], u);
    K[0] = u_min(K[0], u);
}

// ---------------- shared projection formula (bit-identical at all call sites)
__device__ __forceinline__ float4 project_pt(float2 kl, float2 kr, float sc,
                                             const float* __restrict__ q) {
    float dsp = kl.x - kr.x;
    float p0 = q[0]*kl.x  + q[1]*kl.y  + q[2]*dsp  + q[3];
    float p1 = q[4]*kl.x  + q[5]*kl.y  + q[6]*dsp  + q[7];
    float p2 = q[8]*kl.x  + q[9]*kl.y  + q[10]*dsp + q[11];
    float p3 = q[12]*kl.x + q[13]*kl.y + q[14]*dsp + q[15];
    float Wc = fmaxf(p3, 1e-6f);
    float X = p0 / Wc, Y = p1 / Wc, Z = p2 / Wc;
    bool valid = (Z > 100.f) && (Z < 30000.f) && (sc > 0.1f);
    float x  = X / 1000.f;
    float hh = Y / 1000.f;
    float y  = Z / 1000.f;
    float sq = x * x + y * y;
    if (!valid) { x = 0.f; y = 0.f; sq = 1e18f; }   // sentinel
    return make_float4(x, y, sq, hh);
}

// ---------------- bilinear sample, exact reference semantics (fallback) -----
__device__ __forceinline__ float bilin(const float* __restrict__ im, float px, float py) {
    px = fminf(fmaxf(px, 0.f), (float)(WW - 1));
    py = fminf(fmaxf(py, 0.f), (float)(HH - 1));
    float x0f = floorf(px), y0f = floorf(py);
    float fx = px - x0f, fy = py - y0f;
    int x0 = min(max((int)x0f, 0), WW - 1);
    int x1 = min(x0 + 1, WW - 1);
    int y0 = min(max((int)y0f, 0), HH - 1);
    int y1 = min(y0 + 1, HH - 1);
    const float* r0 = im + (size_t)y0 * WW;
    const float* r1 = im + (size_t)y1 * WW;
    float v00 = r0[x0], v01 = r0[x1], v10 = r1[x0], v11 = r1[x1];
    return (v00 * (1.f - fx) + v01 * fx) * (1.f - fy)
         + (v10 * (1.f - fx) + v11 * fx) * fy;
}

// ---------------- Kernel F1: fused projection + patch loss + KNN scan ------
// Three block roles, one launch (was 2 serial launches + gap):
//   blocks [0,125):         projection -> pts[], partialsA, zero batch_acc/dcnt
//   rest, j=i-125, j%3!=2:  patch loss (r8 body verbatim)
//   rest, j%3==2:           KNN scan — SELF-COMPUTES seg/me via project_pt
//                           (no dependency on pts[]; merge reads pts[] next
//                           kernel, after the proj blocks are done)
__global__ __launch_bounds__(256) void fused_all(
    const float* __restrict__ lg, const float* __restrict__ rg,
    const float* __restrict__ kpl, const float* __restrict__ kpr,
    const float* __restrict__ scores, const float* __restrict__ Q,
    float4* __restrict__ pts, unsigned* __restrict__ keybuf,
    float* __restrict__ partialsA, float* __restrict__ partialsB,
    float* __restrict__ batch_acc, unsigned* __restrict__ dcnt)
{
    int i = blockIdx.x;

    if (i < PROJ_BLOCKS) {
        // ================= projection role =================
        if (i == 0) {
            if (threadIdx.x < BB * 4) batch_acc[threadIdx.x] = 0.f;
            if (threadIdx.x == BB * 4) *dcnt = 0u;
        }
        int pt = i * 256 + threadIdx.x;            // < 32000 exactly
        int b  = pt / NN;

        float2 kl = ((const float2* __restrict__)kpl)[pt];
        float2 kr = ((const float2* __restrict__)kpr)[pt];
        float sc  = scores[pt];
        float ydiff = fabsf(kl.y - kr.y);

        pts[pt] = project_pt(kl, kr, sc, Q + b * 16);

        float s0 = sc, s1 = ydiff * sc, s2 = ydiff, s3 = (sc > 0.1f) ? 1.f : 0.f;
        #pragma unroll
        for (int off = 32; off > 0; off >>= 1) {
            s0 += __shfl_down(s0, off, 64);
            s1 += __shfl_down(s1, off, 64);
            s2 += __shfl_down(s2, off, 64);
            s3 += __shfl_down(s3, off, 64);
        }
        __shared__ float redA[4][4];
        int wave = threadIdx.x >> 6, lane = threadIdx.x & 63;
        if (lane == 0) { redA[wave][0]=s0; redA[wave][1]=s1; redA[wave][2]=s2; redA[wave][3]=s3; }
        __syncthreads();
        if (threadIdx.x < 4) {
            int k = threadIdx.x;
            partialsA[i * 4 + k] = redA[0][k] + redA[1][k] + redA[2][k] + redA[3][k];
        }
        return;
    }

    int j = i - PROJ_BLOCKS;
    int m3 = j % 3;

    if (m3 != 2) {
        // ================= patch-loss path (r8 verbatim) =================
        int pid = (j / 3) * 2 + m3;                // [0, 1024)
        if (pid >= PATCH_BLOCKS) return;           // padding (whole block exits)
        int wave = threadIdx.x >> 6, lane = threadIdx.x & 63;
        int rr = lane / 7, ci = lane - rr * 7;     // sample (row,col) for lane<49
        int s00 = lane + rr;                       // = rr*8+ci in 8x8 region
        if (s00 > 54) s00 = 54;                    // keep shfl idx valid for lanes>=49
        int reg_r = lane >> 3, reg_c = lane & 7;   // region-load position

        float a3 = 0.f, a4l = 0.f, a5 = 0.f;       // a3/a5 uniform, a4l per-lane

        for (int it = 0; it < 8; ++it) {
            int pt = pid * 32 + wave * 8 + it;
            int b = pt / NN;
            const float* iml = lg + (size_t)b * (HH * WW);
            const float* imr = rg + (size_t)b * (HH * WW);
            float kxl = kpl[2*pt], kyl = kpl[2*pt+1];
            float kxr = kpr[2*pt], kyr = kpr[2*pt+1];
            float sc  = scores[pt];

            // ---- left patch ----
            float flx = floorf(kxl), fly = floorf(kyl);
            int xbl = (int)flx - 3, ybl = (int)fly - 3;
            float fxl = kxl - flx, fyl = kyl - fly;
            float vl = 0.f;
            if (xbl >= 0 && xbl <= WW-8 && ybl >= 0 && ybl <= HH-8) {  // wave-uniform
                float reg = iml[(size_t)(ybl + reg_r) * WW + xbl + reg_c];
                float v00 = __shfl(reg, s00,     64);
                float v01 = __shfl(reg, s00 + 1, 64);
                float v10 = __shfl(reg, s00 + 8, 64);
                float v11 = __shfl(reg, s00 + 9, 64);
                vl = (v00*(1.f-fxl) + v01*fxl)*(1.f-fyl) + (v10*(1.f-fxl) + v11*fxl)*fyl;
            } else if (lane < 49) {
                vl = bilin(iml, kxl + (float)(ci-3), kyl + (float)(rr-3));
            }
            // ---- right patch ----
            float frx = floorf(kxr), fry = floorf(kyr);
            int xbr = (int)frx - 3, ybr = (int)fry - 3;
            float fxr = kxr - frx, fyr = kyr - fry;
            float vr = 0.f;
            if (xbr >= 0 && xbr <= WW-8 && ybr >= 0 && ybr <= HH-8) {  // wave-uniform
                float reg = imr[(size_t)(ybr + reg_r) * WW + xbr + reg_c];
                float v00 = __shfl(reg, s00,     64);
                float v01 = __shfl(reg, s00 + 1, 64);
                float v10 = __shfl(reg, s00 + 8, 64);
                float v11 = __shfl(reg, s00 + 9, 64);
                vr = (v00*(1.f-fxr) + v01*fxr)*(1.f-fyr) + (v10*(1.f-fxr) + v11*fxr)*fyr;
            } else if (lane < 49) {
                vr = bilin(imr, kxr + (float)(ci-3), kyr + (float)(rr-3));
            }

            float adiff = (lane < 49) ? fabsf(vl - vr) : 0.f;
            float cl = __shfl(vl, 24, 64);   // center sample (3,3) = lane 24
            float cr = __shfl(vr, 24, 64);

            float isb = (cl > 0.02f) ? 1.f : 0.f;   // BRIGHT
            float w   = sc * isb;
            float dc  = fabsf(cl - cr);
            float sl1 = (dc < 1.f) ? 0.5f * dc * dc : dc - 0.5f;

            a3 += w;            // identical on every lane
            a5 += sl1 * w;      // identical on every lane
            a4l += w * adiff;   // per-lane; reduce once below
        }

        #pragma unroll
        for (int off = 32; off > 0; off >>= 1) a4l += __shfl_down(a4l, off, 64);

        __shared__ float red[4][3];
        int wv = threadIdx.x >> 6;
        if (lane == 0) { red[wv][0]=a3; red[wv][1]=a4l * (1.f/49.f); red[wv][2]=a5; }
        __syncthreads();
        if (threadIdx.x < 4) {
            int k = threadIdx.x;
            float v = 0.f;
            if (k < 3) v = red[0][k] + red[1][k] + red[2][k] + red[3][k];
            partialsB[pid * 4 + k] = v;
        }
    } else {
        // ================= KNN scan path: self-computed points =================
        __shared__ float4 seg[SEGLEN];             // 500 candidates = 8 KB
        int sid = j / 3;                           // [0, 512)
        int bx   = sid & 7;
        int r    = sid >> 3;
        int segi = r & (NS - 1);
        int b    = r >> 2;                         // log2(NS)=2
        int mseg0 = segi * SEGLEN;
        const float* q = Q + b * 16;               // wave-uniform -> s_loads

        // compute the candidate segment directly from raw inputs (no pts dep)
        for (int jj = threadIdx.x; jj < SEGLEN; jj += 256) {
            int p = b * NN + mseg0 + jj;
            float2 kl = ((const float2* __restrict__)kpl)[p];
            float2 kr = ((const float2* __restrict__)kpr)[p];
            seg[jj] = project_pt(kl, kr, scores[p], q);
        }

        int n = bx * 256 + threadIdx.x;
        int nc = (n < NN) ? n : (NN - 1);          // clamp for safe loads
        float4 me;
        {
            int p = b * NN + nc;
            float2 kl = ((const float2* __restrict__)kpl)[p];
            float2 kr = ((const float2* __restrict__)kpr)[p];
            me = project_pt(kl, kr, scores[p], q);
        }
        float nx2 = -2.f * me.x, ny2 = -2.f * me.y, sqn = me.z;

        unsigned K[5] = {0xFFFFFFFFu,0xFFFFFFFFu,0xFFFFFFFFu,0xFFFFFFFFu,0xFFFFFFFFu};

        int nb0 = bx * 256;
        bool has_self = (mseg0 < nb0 + 256) && (mseg0 + SEGLEN > nb0);  // block-uniform

        __syncthreads();

        if (has_self) {
            #pragma unroll 5
            for (int mm = 0; mm < SEGLEN; ++mm) {
                float4 o = seg[mm];                // LDS broadcast read
                int m = mseg0 + mm;
                float t = fmaf(ny2, o.y, o.z);
                t = fmaf(nx2, o.x, t);
                float d2 = fmaxf(t + sqn, 1e-12f);
                unsigned u = (__float_as_uint(d2) & 0xFFFFF800u) | (unsigned)m;
                u = (m == n) ? 0xFFFFFFFFu : u;    // exclude self
                ins5(K, u);
            }
        } else {
            #pragma unroll 5
            for (int mm = 0; mm < SEGLEN; ++mm) {
                float4 o = seg[mm];                // LDS broadcast read
                int m = mseg0 + mm;
                float t = fmaf(ny2, o.y, o.z);
                t = fmaf(nx2, o.x, t);
                float d2 = fmaxf(t + sqn, 1e-12f);
                unsigned u = (__float_as_uint(d2) & 0xFFFFF800u) | (unsigned)m;
                ins5(K, u);
            }
        }

        if (n < NN) {
            size_t base = (size_t)((b * NS + segi) * 5) * KSTRIDE + n;
            keybuf[base              ] = K[0];
            keybuf[base + KSTRIDE    ] = K[1];
            keybuf[base + KSTRIDE * 2] = K[2];
            keybuf[base + KSTRIDE * 3] = K[3];
            keybuf[base + KSTRIDE * 4] = K[4];
        }
    }
}

// ---------------- Kernel F2: merge + fused final epilogue -------------------
// NS compile-time: 20 keybuf loads fully unrolled, max MLP (r8-verified fix).
__global__ __launch_bounds__(256) void knn_merge_final(
    const float4* __restrict__ pts, const unsigned* __restrict__ keybuf,
    float* __restrict__ batch_acc, unsigned* __restrict__ dcnt,
    const float* __restrict__ partialsA, const float* __restrict__ partialsB,
    float* __restrict__ out)
{
    int b = blockIdx.y;
    int n = blockIdx.x * 256 + threadIdx.x;

    float ls = 0.f, pen = 0.f, hacc = 0.f, cnt = 0.f;
    if (n < NN) {
        float4 me = pts[b * NN + n];
        if (me.z < 1e17f) {
            unsigned K[5] = {0xFFFFFFFFu,0xFFFFFFFFu,0xFFFFFFFFu,0xFFFFFFFFu,0xFFFFFFFFu};
            #pragma unroll
            for (int s = 0; s < NS; ++s) {
                #pragma unroll
                for (int jj = 0; jj < 5; ++jj) {
                    unsigned u = keybuf[(size_t)((b * NS + s) * 5 + jj) * KSTRIDE + n];
                    ins5(K, u);
                }
            }
            float hsum = 0.f;
            #pragma unroll
            for (int t = 0; t < 5; ++t) {
                int idx = (int)(K[t] & 2047u);
                float4 o = pts[b * NN + idx];
                float dot = me.x * o.x + me.y * o.y;
                float d2 = (me.z + o.z) - 2.f * dot;        // exact recompute
                float nd = fmaxf(sqrtf(fmaxf(d2, 1e-12f)), 0.001f);
                hsum += o.w;
                pen  += fmaxf(fabsf(o.w - me.w) / nd - 0.4f, 0.f);
            }
            float lm = hsum / 5.f;
            float dd = fabsf(me.w - lm);
            ls = (dd < 0.01f) ? 0.5f * dd * dd / 0.01f : dd - 0.005f;  // smooth_l1 beta=0.01
            hacc = me.w;
            cnt  = 1.f;
        }
    }

    #pragma unroll
    for (int off = 32; off > 0; off >>= 1) {
        ls   += __shfl_down(ls,   off, 64);
        pen  += __shfl_down(pen,  off, 64);
        hacc += __shfl_down(hacc, off, 64);
        cnt  += __shfl_down(cnt,  off, 64);
    }
    __shared__ float r2[4][4];
    int wave = threadIdx.x >> 6, lane = threadIdx.x & 63;
    if (lane == 0) { r2[wave][0]=cnt; r2[wave][1]=ls; r2[wave][2]=pen; r2[wave][3]=hacc; }
    __syncthreads();
    if (threadIdx.x == 0) {
        float tc = r2[0][0]+r2[1][0]+r2[2][0]+r2[3][0];
        float tl = r2[0][1]+r2[1][1]+r2[2][1]+r2[3][1];
        float tp = r2[0][2]+r2[1][2]+r2[2][2]+r2[3][2];
        float th = r2[0][3]+r2[1][3]+r2[2][3]+r2[3][3];
        atomicAdd(&batch_acc[b * 4 + 0], tc);
        atomicAdd(&batch_acc[b * 4 + 1], tl);
        atomicAdd(&batch_acc[b * 4 + 2], tp);
        atomicAdd(&batch_acc[b * 4 + 3], th);
    }

    // ---- done-counter: last block runs the final scalar epilogue ----
    __shared__ int lastf;
    __threadfence();                                  // release our atomics
    if (threadIdx.x == 0) {
        unsigned old = atomicAdd(dcnt, 1u);
        lastf = (old == (unsigned)(8 * BB - 1)) ? 1 : 0;
    }
    __syncthreads();
    if (!lastf) return;
    __threadfence();                                  // acquire others' atomics

    float s[7] = {0,0,0,0,0,0,0};
    for (int rI = threadIdx.x; rI < PROJ_BLOCKS; rI += 256) {
        s[0] += partialsA[rI * 4 + 0];
        s[1] += partialsA[rI * 4 + 1];
        s[2] += partialsA[rI * 4 + 2];
        s[3] += partialsA[rI * 4 + 3];
    }
    for (int rI = threadIdx.x; rI < PATCH_BLOCKS; rI += 256) {
        s[4] += partialsB[rI * 4 + 0];
        s[5] += partialsB[rI * 4 + 1];
        s[6] += partialsB[rI * 4 + 2];
    }
    #pragma unroll
    for (int off = 32; off > 0; off >>= 1) {
        #pragma unroll
        for (int k = 0; k < 7; ++k) s[k] += __shfl_down(s[k], off, 64);
    }
    __shared__ float ws2[4][7];
    if (lane == 0) {
        #pragma unroll
        for (int k = 0; k < 7; ++k) ws2[wave][k] = s[k];
    }
    __syncthreads();
    if (threadIdx.x == 0) {
        float t[7];
        #pragma unroll
        for (int k = 0; k < 7; ++k)
            t[k] = ws2[0][k] + ws2[1][k] + ws2[2][k] + ws2[3][k];
        float ssc = t[0], yds = t[1], yd = t[2], cnts = t[3];
        float wsum = t[4], dw = t[5], iw = t[6];

        float l_epi = (ssc > 1e-4f) ? yds / fmaxf(ssc, 1e-12f) : yd / (float)NPT;
        float safe = fmaxf(wsum, 1e-12f);
        float l_photo = (wsum > 1e-4f) ? (dw / safe + iw / safe) : 0.f;

        float als = 0.f, alsl = 0.f, alz = 0.f, okc = 0.f;
        for (int bb = 0; bb < BB; ++bb) {
            float nvf  = __hip_atomic_load(&batch_acc[bb*4+0], __ATOMIC_RELAXED, __HIP_MEMORY_SCOPE_AGENT);
            float lsb  = __hip_atomic_load(&batch_acc[bb*4+1], __ATOMIC_RELAXED, __HIP_MEMORY_SCOPE_AGENT);
            float penb = __hip_atomic_load(&batch_acc[bb*4+2], __ATOMIC_RELAXED, __HIP_MEMORY_SCOPE_AGENT);
            float hb   = __hip_atomic_load(&batch_acc[bb*4+3], __ATOMIC_RELAXED, __HIP_MEMORY_SCOPE_AGENT);
            float nv = fmaxf(nvf, 1.f);
            float ok = (nvf >= 10.f) ? 1.f : 0.f;
            als  += ok * (lsb / nv);
            alsl += ok * (penb / (nv * 5.f));   // K = 5
            alz  += ok * fabsf(hb / nv);
            okc  += ok;
        }
        float nb = fmaxf(okc, 1.f);
        bool gate = (cnts >= 10.f) && (okc > 0.f);
        out[0] = l_photo;
        out[1] = l_epi;
        out[2] = gate ? als / nb : 0.f;
        out[3] = gate ? alsl / nb : 0.f;
        out[4] = gate ? alz / nb : 0.f;
    }
}

extern "C" void kernel_launch(void* const* d_in, const int* in_sizes, int n_in,
                              void* d_out, int out_size, void* d_ws, size_t ws_size,
                              hipStream_t stream)
{
    const float* lg     = (const float*)d_in[0];
    const float* rg     = (const float*)d_in[1];
    const float* kpl    = (const float*)d_in[2];
    const float* kpr    = (const float*)d_in[3];
    const float* scores = (const float*)d_in[4];
    const float* Q      = (const float*)d_in[5];
    float* out = (float*)d_out;

    char* ws = (char*)d_ws;
    float4*   pts       = (float4*)ws;                   // 512000 B
    float*    partialsA = (float*)(ws + 512000);         // 125*4*4 = 2000 B (pad 2048)
    float*    partialsB = (float*)(ws + 514048);         // 1000*4*4 = 16000 B (pad 16384)
    float*    batch_acc = (float*)(ws + 530432);         // 16*4*4 = 256 B
    unsigned* dcnt      = (unsigned*)(ws + 530688);      // 4 B (pad 256)
    unsigned* keybuf    = (unsigned*)(ws + 530944);      // 16*4*5*2048*4 = 2,621,440 B
                                                         // total 3.15 MB << ws

    fused_all<<<FUSED_BLOCKS, 256, 0, stream>>>(
        lg, rg, kpl, kpr, scores, Q, pts, keybuf,
        partialsA, partialsB, batch_acc, dcnt);
    knn_merge_final<<<dim3(8, BB), 256, 0, stream>>>(pts, keybuf, batch_acc, dcnt,
                                                     partialsA, partialsB, out);
}